// Round 14
// baseline (639.762 us; speedup 1.0000x reference)
//
#include <hip/hip_runtime.h>
#include <cstdint>
#include <cstddef>

#define NE 8
#define DMODEL 768
#define MLPDIM 3072
#define NDET 16384
#define NCLS 4096
#define NTOK 20480
#define ROWS_PER_E 5120   /* 16*256 (det) + 8*128 (cls) */
#define TOT_ROWS 40960

typedef float f32x4 __attribute__((ext_vector_type(4)));
typedef __bf16 bf16x8 __attribute__((ext_vector_type(8)));

__device__ __forceinline__ unsigned short f2bf(float f) {
    unsigned u = __float_as_uint(f);
    u += 0x7FFFu + ((u >> 16) & 1u);   // RNE
    return (unsigned short)(u >> 16);
}
__device__ __forceinline__ float bf2f(unsigned v) {
    return __uint_as_float(v << 16);
}
__device__ __forceinline__ float gelu_f(float x) {
    // jax.nn.gelu approximate=True. Exact identity: 0.5*(1+tanh(u)) == sigmoid(2u)
    // => gelu = x / (1 + exp(-2u)), u = 0.79788456*(x + 0.044715 x^3).
    float u = x * (0.7978845608028654f + 0.0356774081099f * x * x);
    return x * __frcp_rn(1.0f + __expf(-2.0f * u));
}

// async global->LDS, 16B per lane; dst is wave-uniform base, HW adds lane*16
__device__ __forceinline__ void gload16(const void* g, void* l) {
    __builtin_amdgcn_global_load_lds(
        (const __attribute__((address_space(1))) unsigned int*)g,
        (__attribute__((address_space(3))) unsigned int*)l, 16, 0, 0);
}

// ---------------- router (fp32) + x->bf16 conversion fused ----------------
__global__ void k_router(const float* __restrict__ xd, const float* __restrict__ xc,
                         const float* __restrict__ wrd, const float* __restrict__ wrc,
                         ushort* __restrict__ xbf,
                         int* __restrict__ e1, int* __restrict__ e2,
                         float* __restrict__ g1, float* __restrict__ g2) {
    int wave = threadIdx.x >> 6, lane = threadIdx.x & 63;
    int t = blockIdx.x * 4 + wave;
    if (t >= NTOK) return;
    const float* xrow;
    const float* w;
    if (t < NDET) { xrow = xd + (size_t)t * DMODEL; w = wrd; }
    else          { xrow = xc + (size_t)(t - NDET) * DMODEL; w = wrc; }
    ushort* xbrow = xbf + (size_t)t * DMODEL;
    float acc[8];
    #pragma unroll
    for (int e = 0; e < 8; e++) acc[e] = 0.0f;
    #pragma unroll
    for (int kk = 0; kk < DMODEL / 64; kk++) {
        int k = kk * 64 + lane;
        float xv = xrow[k];
        xbrow[k] = f2bf(xv);              // fused bf16 conversion
        const float* wr = w + k * 8;
        #pragma unroll
        for (int e = 0; e < 8; e++) acc[e] += xv * wr[e];
    }
    #pragma unroll
    for (int e = 0; e < 8; e++) {
        #pragma unroll
        for (int off = 32; off > 0; off >>= 1) acc[e] += __shfl_xor(acc[e], off);
    }
    // top-2 with lower-index tie-break (lax.top_k)
    int i1 = 0; float v1 = acc[0];
    #pragma unroll
    for (int e = 1; e < 8; e++) if (acc[e] > v1) { v1 = acc[e]; i1 = e; }
    int i2 = -1; float v2 = -1e30f;
    #pragma unroll
    for (int e = 0; e < 8; e++) if (e != i1 && acc[e] > v2) { v2 = acc[e]; i2 = e; }
    float Z = 0.0f;
    #pragma unroll
    for (int e = 0; e < 8; e++) Z += __expf(acc[e] - v1);
    if (lane == 0) {
        e1[t] = i1; e2[t] = i2;
        g1[t] = 1.0f / Z;
        g2[t] = __expf(v2 - v1) / Z;
    }
}

// ---------------- w [E][K][N] fp32 -> [E][N][K] bf16 (float4 loads) ----------------
__global__ void k_transpose_bf(const float* __restrict__ in, ushort* __restrict__ out,
                               int K, int N) {
    __shared__ float tile[32][33];
    int e = blockIdx.z;
    const float* A = in + (size_t)e * K * N;
    ushort* B = out + (size_t)e * N * K;
    int n0 = blockIdx.x * 32, k0 = blockIdx.y * 32;
    int tx = threadIdx.x, ty = threadIdx.y;   // (8,32)
    float4 v = *(const float4*)(A + (size_t)(k0 + ty) * N + n0 + tx * 4);
    tile[ty][tx * 4 + 0] = v.x; tile[ty][tx * 4 + 1] = v.y;
    tile[ty][tx * 4 + 2] = v.z; tile[ty][tx * 4 + 3] = v.w;
    __syncthreads();
    ushort4 o;
    o.x = f2bf(tile[tx * 4 + 0][ty]);
    o.y = f2bf(tile[tx * 4 + 1][ty]);
    o.z = f2bf(tile[tx * 4 + 2][ty]);
    o.w = f2bf(tile[tx * 4 + 3][ty]);
    *(ushort4*)(B + (size_t)(n0 + ty) * K + k0 + tx * 4) = o;
}

// ---------------- capacity scan: one wave per group, k-major order ----------------
__global__ void k_scan(const int* __restrict__ e1, const int* __restrict__ e2,
                       int* __restrict__ slot_map, int* __restrict__ r1, int* __restrict__ r2) {
    int g = blockIdx.x;          // 0..15 det, 16..23 cls
    int lane = threadIdx.x;      // 64 threads
    int S, C, base;
    if (g < 16) { S = 1024; C = 256; base = g * 1024; }
    else        { S = 512;  C = 128; base = NDET + (g - 16) * 512; }
    int cnt[8];
    #pragma unroll
    for (int e = 0; e < 8; e++) cnt[e] = 0;
    unsigned long long lower = (lane == 0) ? 0ULL : ((~0ULL) >> (64 - lane));
    int nch = (2 * S) >> 6;
    for (int ch = 0; ch < nch; ch++) {
        int n = ch * 64 + lane;
        int k = (n >= S) ? 1 : 0;
        int s = n - k * S;
        int tok = base + s;
        int e = k ? e2[tok] : e1[tok];
        int pos = 0;
        #pragma unroll
        for (int ee = 0; ee < 8; ee++) {
            unsigned long long m = __ballot(e == ee);
            if (e == ee) pos = cnt[ee] + __popcll(m & lower);
            cnt[ee] += __popcll(m);
        }
        int r = -1;
        if (pos < C) {
            int local = (g < 16) ? (g * 256 + pos) : (4096 + (g - 16) * 128 + pos);
            r = e * ROWS_PER_E + local;
            slot_map[r] = tok;
        }
        if (k == 0) r1[tok] = r; else r2[tok] = r;
    }
}

// ---------------- GEMM: 128x128 tile, BK=32 double-buffered, 4 waves, 64x64/wave ----
// R13 chassis (best: 569us) with the K-loop converted to a BK=32 double-buffer in
// the SAME 32KB LDS (4 x 8KB named buffers): per tile {STAGE(t+1 -> other buf)
// FIRST; read frags; 16 MFMA; vmcnt(0)+barrier}. Load flight grows from ~300cyc
// (post-barrier2 only) to a full tile (~475cyc) -> covers L2 fully, most of HBM;
// the old barrier-1 drain-against-fresh-loads is gone. Sync/MFMA ratio unchanged.
// WAR-safe (R10-proven): writes target the buffer whose reads completed before
// the previous barrier; reads guarded by own vmcnt(0) + rendezvous.
// Swizzle (4 chunks/row): physical chunk p of row r holds logical chunk p^(r&3);
// read fetches chunk kq^(row&3) -> uniform 8-way spread over 16B bank-groups.
// MFAST grouped m-fastest walk for GEMM1 (R13-verified: FETCH 195->144MB).
// MODE 0: A = xbf gathered via slot_map -> h=gelu(A@B+b) (chunk-local rows)
// MODE 1: A = h (chunk-local) -> y[global row] = A@B+b
template<int KTOT, int NTOT, int MODE, bool MFAST>
__global__ __launch_bounds__(256, 4) void k_gemm(
    const ushort* __restrict__ Asrc, const int* __restrict__ slot_map,
    const ushort* __restrict__ wtBase, const float* __restrict__ biasBase,
    ushort* __restrict__ Cdst, int eBase, int gm) {
    constexpr int KT = KTOT / 32;            // 24 (GEMM1) / 96 (GEMM2), both even
    constexpr int NBN = NTOT / 128;
    __shared__ __align__(1024) ushort As0[128 * 32];   // 8 KB each
    __shared__ __align__(1024) ushort As1[128 * 32];
    __shared__ __align__(1024) ushort Bs0[128 * 32];
    __shared__ __align__(1024) ushort Bs1[128 * 32];

    // bijective XCD-chunked swizzle (gridDim.x % 8 == 0)
    const int q = gridDim.x >> 3;
    const int id2 = (blockIdx.x & 7) * q + (blockIdx.x >> 3);
    int mb, nb;
    if (MFAST) {
        // grouped m-fastest: group = gm consecutive mbs; within group, mb fastest
        int bpg = gm * NBN;
        int g = id2 / bpg, r = id2 - g * bpg;
        nb = r / gm;
        mb = g * gm + (r - nb * gm);
    } else {
        mb = id2 / NBN;
        nb = id2 - mb * NBN;
    }
    const int e = eBase + mb / (ROWS_PER_E / 128);
    const int m0 = mb * 128;                     // chunk-local row base
    const int rbase = eBase * ROWS_PER_E + m0;   // global expert-row base
    const int n0 = nb * 128;
    const ushort* Bt = wtBase + (size_t)e * KTOT * NTOT;
    const float* bias = biasBase + (size_t)e * NTOT;

    const int t = threadIdx.x, lane = t & 63, wave = t >> 6;
    const int g16 = lane >> 2;         // row within 16-row gload slab
    const int p4 = lane & 3;           // physical 16B chunk this lane fills
    const int swz = ((p4 ^ (g16 & 3)) << 4);   // byte off of LOGICAL chunk to fetch

    // staging: wave w covers A rows [w*32,w*32+32) and B rows [w*32,w*32+32),
    // 16 rows per gload -> 2 A-gloads + 2 B-gloads per wave per K-tile
    const char* aS[2];
    const char* bS[2];
    #pragma unroll
    for (int j = 0; j < 2; j++) {
        int r = wave * 32 + j * 16 + g16;
        size_t arow;
        if (MODE == 0) { int tk = slot_map[rbase + r]; arow = (size_t)(tk < 0 ? 0 : tk); }
        else           { arow = (size_t)(m0 + r); }
        aS[j] = (const char*)(Asrc + arow * KTOT) + swz;
        bS[j] = (const char*)(Bt + (size_t)(n0 + r) * KTOT) + swz;
    }

    auto STAGE = [&](int kt, ushort* WA, ushort* WB) {
        size_t o = (size_t)kt * 64;    // 32 bf16 = 64 B per row per K-tile
        #pragma unroll
        for (int j = 0; j < 2; j++) {
            gload16(aS[j] + o, WA + (wave * 32 + j * 16) * 32);
            gload16(bS[j] + o, WB + (wave * 32 + j * 16) * 32);
        }
    };

    const int wr = wave >> 1, wc = wave & 1;   // wave grid 2(m) x 2(n), out 64x64
    const int l15 = lane & 15, kq = lane >> 4;
    const int ch = (kq ^ (l15 & 3)) << 3;      // swizzled ushort offset (row&3 = l15&3)

    f32x4 acc[4][4] = {};

    // body for K-tile kt: stage kt+1 into W first, compute from R, one sync point
    auto BODY = [&](int kt, const ushort* RA, const ushort* RB, ushort* WA, ushort* WB) {
        const bool last = (kt + 1 >= KT);
        if (!last) STAGE(kt + 1, WA, WB);      // issue first: full-tile flight
        bf16x8 af[4], bfr[4];
        #pragma unroll
        for (int mi = 0; mi < 4; mi++)
            af[mi] = *(const bf16x8*)(&RA[(wr * 64 + mi * 16 + l15) * 32 + ch]);
        #pragma unroll
        for (int nf = 0; nf < 4; nf++)
            bfr[nf] = *(const bf16x8*)(&RB[(wc * 64 + nf * 16 + l15) * 32 + ch]);
        __builtin_amdgcn_s_setprio(1);
        #pragma unroll
        for (int mi = 0; mi < 4; mi++) {
            #pragma unroll
            for (int nf = 0; nf < 4; nf++)
                acc[mi][nf] = __builtin_amdgcn_mfma_f32_16x16x32_bf16(
                    af[mi], bfr[nf], acc[mi][nf], 0, 0, 0);
        }
        __builtin_amdgcn_s_setprio(0);
        if (!last) {
            asm volatile("s_waitcnt vmcnt(0)" ::: "memory");   // kt+1's 4 gloads landed
            __builtin_amdgcn_s_barrier();                      // all waves ready; reads done
        }
    };

    // prologue: stage tile 0, drain, rendezvous
    STAGE(0, As0, Bs0);
    asm volatile("s_waitcnt vmcnt(0)" ::: "memory");
    __builtin_amdgcn_s_barrier();

    for (int kt = 0; kt < KT; kt += 2) {
        BODY(kt,     As0, Bs0, As1, Bs1);
        BODY(kt + 1, As1, Bs1, As0, Bs0);
    }

    // epilogue: C/D layout col=lane&15, row=(lane>>4)*4+j  (verified)
    const int ccolb = n0 + wc * 64 + l15;
    float bv[4];
    #pragma unroll
    for (int nf = 0; nf < 4; nf++) bv[nf] = bias[ccolb + nf * 16];

    const int rowb = (MODE == 0 ? m0 : rbase) + wr * 64 + (lane >> 4) * 4;
    #pragma unroll
    for (int mi = 0; mi < 4; mi++) {
        #pragma unroll
        for (int j = 0; j < 4; j++) {
            size_t roff = (size_t)(rowb + mi * 16 + j) * NTOT;
            #pragma unroll
            for (int nf = 0; nf < 4; nf++) {
                float v = acc[mi][nf][j] + bv[nf];
                if (MODE == 0) v = gelu_f(v);
                Cdst[roff + ccolb + nf * 16] = f2bf(v);
            }
        }
    }
}

// ---------------- combine: out[token] = g1*y[r1] + g2*y[r2] ----------------
__global__ void k_combine(const ushort* __restrict__ y,
                          const int* __restrict__ r1, const int* __restrict__ r2,
                          const float* __restrict__ g1, const float* __restrict__ g2,
                          float* __restrict__ out) {
    int t = blockIdx.x;
    int d = threadIdx.x;          // 192 threads, 4 floats each
    int a = r1[t], b = r2[t];
    float wa = g1[t], wb = g2[t];
    size_t opos;
    if (t < NDET) { int bb = t >> 10, s = t & 1023; opos = ((size_t)bb * 1280 + s) * 768; }
    else { int tt = t - NDET; int bb = tt >> 8, s = tt & 255; opos = ((size_t)bb * 1280 + 1024 + s) * 768; }
    int di = d * 4;
    float4 o = make_float4(0.f, 0.f, 0.f, 0.f);
    if (a >= 0) {
        uint2 v = *(const uint2*)(y + (size_t)a * 768 + di);
        o.x += wa * bf2f(v.x & 0xffffu); o.y += wa * bf2f(v.x >> 16);
        o.z += wa * bf2f(v.y & 0xffffu); o.w += wa * bf2f(v.y >> 16);
    }
    if (b >= 0) {
        uint2 v = *(const uint2*)(y + (size_t)b * 768 + di);
        o.x += wb * bf2f(v.x & 0xffffu); o.y += wb * bf2f(v.x >> 16);
        o.z += wb * bf2f(v.y & 0xffffu); o.w += wb * bf2f(v.y >> 16);
    }
    *(float4*)(out + opos + di) = o;
}

extern "C" void kernel_launch(void* const* d_in, const int* in_sizes, int n_in,
                              void* d_out, int out_size, void* d_ws, size_t ws_size,
                              hipStream_t stream) {
    const float* xd  = (const float*)d_in[0];
    const float* xc  = (const float*)d_in[1];
    const float* wrd = (const float*)d_in[2];
    const float* wrc = (const float*)d_in[3];
    const float* w1  = (const float*)d_in[4];
    const float* b1  = (const float*)d_in[5];
    const float* w2  = (const float*)d_in[6];
    const float* b2  = (const float*)d_in[7];
    float* out = (float*)d_out;

    size_t off = 0;
    char* base = (char*)d_ws;
    auto alloc = [&](size_t bytes) -> char* {
        char* r = base + off;
        off += (bytes + 255) & ~(size_t)255;
        return r;
    };
    ushort* xbf = (ushort*)alloc((size_t)NTOK * DMODEL * 2);
    ushort* w1t = (ushort*)alloc((size_t)NE * MLPDIM * DMODEL * 2);
    ushort* w2t = (ushort*)alloc((size_t)NE * DMODEL * MLPDIM * 2);
    ushort* y   = (ushort*)alloc((size_t)TOT_ROWS * DMODEL * 2);
    int*   slot_map = (int*)alloc((size_t)TOT_ROWS * 4);
    int*   e1 = (int*)alloc((size_t)NTOK * 4);
    int*   e2 = (int*)alloc((size_t)NTOK * 4);
    float* g1 = (float*)alloc((size_t)NTOK * 4);
    float* g2 = (float*)alloc((size_t)NTOK * 4);
    int*   r1 = (int*)alloc((size_t)NTOK * 4);
    int*   r2 = (int*)alloc((size_t)NTOK * 4);

    // pick the largest expert-chunk whose h buffer fits the workspace
    const size_t h_per_e = (size_t)ROWS_PER_E * MLPDIM * 2;   // 31.5 MB
    int chunkE = 0;
    for (int c = NE; c >= 2; c >>= 1)
        if (off + c * h_per_e <= ws_size) { chunkE = c; break; }
    if (!chunkE) return;
    ushort* h = (ushort*)alloc((size_t)chunkE * h_per_e);

    hipMemsetAsync(slot_map, 0xFF, (size_t)TOT_ROWS * 4, stream);   // -1 = empty

    k_router<<<NTOK / 4, 256, 0, stream>>>(xd, xc, wrd, wrc, xbf, e1, e2, g1, g2);
    k_transpose_bf<<<dim3(MLPDIM / 32, DMODEL / 32, NE), dim3(8, 32), 0, stream>>>(w1, w1t, DMODEL, MLPDIM);
    k_transpose_bf<<<dim3(DMODEL / 32, MLPDIM / 32, NE), dim3(8, 32), 0, stream>>>(w2, w2t, MLPDIM, DMODEL);
    k_scan<<<24, 64, 0, stream>>>(e1, e2, slot_map, r1, r2);

    for (int e0 = 0; e0 < NE; e0 += chunkE) {
        int nmb = chunkE * (ROWS_PER_E / 128);               // 128-row m-blocks in chunk
        int gm = (nmb % 20 == 0) ? 20 : 10;                  // A-group: gm*192KB <= 4MB L2
        k_gemm<DMODEL, MLPDIM, 0, true><<<nmb * (MLPDIM / 128), 256, 0, stream>>>(
            xbf, slot_map, w1t, b1, h, e0, gm);
        k_gemm<MLPDIM, DMODEL, 1, false><<<nmb * (DMODEL / 128), 256, 0, stream>>>(
            h, slot_map, w2t, b2, y, e0, 0);
    }

    k_combine<<<NTOK, 192, 0, stream>>>(y, r1, r2, g1, g2, out);
}

// Round 15
// 635.672 us; speedup vs baseline: 1.0064x; 1.0064x over previous
//
#include <hip/hip_runtime.h>
#include <cstdint>
#include <cstddef>

#define NE 8
#define DMODEL 768
#define MLPDIM 3072
#define NDET 16384
#define NCLS 4096
#define NTOK 20480
#define ROWS_PER_E 5120   /* 16*256 (det) + 8*128 (cls) */
#define TOT_ROWS 40960

typedef float f32x4 __attribute__((ext_vector_type(4)));
typedef __bf16 bf16x8 __attribute__((ext_vector_type(8)));

__device__ __forceinline__ unsigned short f2bf(float f) {
    unsigned u = __float_as_uint(f);
    u += 0x7FFFu + ((u >> 16) & 1u);   // RNE
    return (unsigned short)(u >> 16);
}
__device__ __forceinline__ float bf2f(unsigned v) {
    return __uint_as_float(v << 16);
}
__device__ __forceinline__ float gelu_f(float x) {
    // jax.nn.gelu approximate=True. Exact identity: 0.5*(1+tanh(u)) == sigmoid(2u)
    // => gelu = x / (1 + exp(-2u)), u = 0.79788456*(x + 0.044715 x^3).
    float u = x * (0.7978845608028654f + 0.0356774081099f * x * x);
    return x * __frcp_rn(1.0f + __expf(-2.0f * u));
}

// async global->LDS, 16B per lane; dst is wave-uniform base, HW adds lane*16
__device__ __forceinline__ void gload16(const void* g, void* l) {
    __builtin_amdgcn_global_load_lds(
        (const __attribute__((address_space(1))) unsigned int*)g,
        (__attribute__((address_space(3))) unsigned int*)l, 16, 0, 0);
}

// ---------------- router (fp32) + x->bf16 conversion fused ----------------
__global__ void k_router(const float* __restrict__ xd, const float* __restrict__ xc,
                         const float* __restrict__ wrd, const float* __restrict__ wrc,
                         ushort* __restrict__ xbf,
                         int* __restrict__ e1, int* __restrict__ e2,
                         float* __restrict__ g1, float* __restrict__ g2) {
    int wave = threadIdx.x >> 6, lane = threadIdx.x & 63;
    int t = blockIdx.x * 4 + wave;
    if (t >= NTOK) return;
    const float* xrow;
    const float* w;
    if (t < NDET) { xrow = xd + (size_t)t * DMODEL; w = wrd; }
    else          { xrow = xc + (size_t)(t - NDET) * DMODEL; w = wrc; }
    ushort* xbrow = xbf + (size_t)t * DMODEL;
    float acc[8];
    #pragma unroll
    for (int e = 0; e < 8; e++) acc[e] = 0.0f;
    #pragma unroll
    for (int kk = 0; kk < DMODEL / 64; kk++) {
        int k = kk * 64 + lane;
        float xv = xrow[k];
        xbrow[k] = f2bf(xv);              // fused bf16 conversion
        const float* wr = w + k * 8;
        #pragma unroll
        for (int e = 0; e < 8; e++) acc[e] += xv * wr[e];
    }
    #pragma unroll
    for (int e = 0; e < 8; e++) {
        #pragma unroll
        for (int off = 32; off > 0; off >>= 1) acc[e] += __shfl_xor(acc[e], off);
    }
    // top-2 with lower-index tie-break (lax.top_k)
    int i1 = 0; float v1 = acc[0];
    #pragma unroll
    for (int e = 1; e < 8; e++) if (acc[e] > v1) { v1 = acc[e]; i1 = e; }
    int i2 = -1; float v2 = -1e30f;
    #pragma unroll
    for (int e = 0; e < 8; e++) if (e != i1 && acc[e] > v2) { v2 = acc[e]; i2 = e; }
    float Z = 0.0f;
    #pragma unroll
    for (int e = 0; e < 8; e++) Z += __expf(acc[e] - v1);
    if (lane == 0) {
        e1[t] = i1; e2[t] = i2;
        g1[t] = 1.0f / Z;
        g2[t] = __expf(v2 - v1) / Z;
    }
}

// ---------------- w [E][K][N] fp32 -> [E][N][K] bf16 (float4 loads) ----------------
__global__ void k_transpose_bf(const float* __restrict__ in, ushort* __restrict__ out,
                               int K, int N) {
    __shared__ float tile[32][33];
    int e = blockIdx.z;
    const float* A = in + (size_t)e * K * N;
    ushort* B = out + (size_t)e * N * K;
    int n0 = blockIdx.x * 32, k0 = blockIdx.y * 32;
    int tx = threadIdx.x, ty = threadIdx.y;   // (8,32)
    float4 v = *(const float4*)(A + (size_t)(k0 + ty) * N + n0 + tx * 4);
    tile[ty][tx * 4 + 0] = v.x; tile[ty][tx * 4 + 1] = v.y;
    tile[ty][tx * 4 + 2] = v.z; tile[ty][tx * 4 + 3] = v.w;
    __syncthreads();
    ushort4 o;
    o.x = f2bf(tile[tx * 4 + 0][ty]);
    o.y = f2bf(tile[tx * 4 + 1][ty]);
    o.z = f2bf(tile[tx * 4 + 2][ty]);
    o.w = f2bf(tile[tx * 4 + 3][ty]);
    *(ushort4*)(B + (size_t)(n0 + ty) * K + k0 + tx * 4) = o;
}

// ---------------- capacity scan: one wave per group, k-major order ----------------
__global__ void k_scan(const int* __restrict__ e1, const int* __restrict__ e2,
                       int* __restrict__ slot_map, int* __restrict__ r1, int* __restrict__ r2) {
    int g = blockIdx.x;          // 0..15 det, 16..23 cls
    int lane = threadIdx.x;      // 64 threads
    int S, C, base;
    if (g < 16) { S = 1024; C = 256; base = g * 1024; }
    else        { S = 512;  C = 128; base = NDET + (g - 16) * 512; }
    int cnt[8];
    #pragma unroll
    for (int e = 0; e < 8; e++) cnt[e] = 0;
    unsigned long long lower = (lane == 0) ? 0ULL : ((~0ULL) >> (64 - lane));
    int nch = (2 * S) >> 6;
    for (int ch = 0; ch < nch; ch++) {
        int n = ch * 64 + lane;
        int k = (n >= S) ? 1 : 0;
        int s = n - k * S;
        int tok = base + s;
        int e = k ? e2[tok] : e1[tok];
        int pos = 0;
        #pragma unroll
        for (int ee = 0; ee < 8; ee++) {
            unsigned long long m = __ballot(e == ee);
            if (e == ee) pos = cnt[ee] + __popcll(m & lower);
            cnt[ee] += __popcll(m);
        }
        int r = -1;
        if (pos < C) {
            int local = (g < 16) ? (g * 256 + pos) : (4096 + (g - 16) * 128 + pos);
            r = e * ROWS_PER_E + local;
            slot_map[r] = tok;
        }
        if (k == 0) r1[tok] = r; else r2[tok] = r;
    }
}

// ---------------- GEMM: 128x128 tile, BK=32 double-buffered, 4 waves, 64x64/wave ----
// R14 structure with the CORRECTED swizzle. Bank math for 64B rows: row r's
// bank-base = (r*16)%32 alternates with row PARITY, so the XOR key must not
// alias parity: f(r) = (r>>1)&3. Even rows 0,2,4,6 -> chunks f=0,1,2,3 (uniform);
// per wave-b128: 8 (parity x chunk) slots x 8 lanes x 16B = 8 dwords/bank = the
// 1KB minimum -> conflict-free. (R14's f=r&3 gave even rows only 2 chunks ->
// 1.18e7 conflicts = the whole 151-vs-126us regression; FETCH had improved.)
// Per tile {STAGE(t+1 -> other buf) FIRST; read frags; 16 MFMA; vmcnt(0)+bar}.
// WAR-safe (R10/R14-proven). MFAST grouped m-fastest walk for GEMM1 (R13).
// MODE 0: A = xbf gathered via slot_map -> h=gelu(A@B+b) (chunk-local rows)
// MODE 1: A = h (chunk-local) -> y[global row] = A@B+b
template<int KTOT, int NTOT, int MODE, bool MFAST>
__global__ __launch_bounds__(256, 4) void k_gemm(
    const ushort* __restrict__ Asrc, const int* __restrict__ slot_map,
    const ushort* __restrict__ wtBase, const float* __restrict__ biasBase,
    ushort* __restrict__ Cdst, int eBase, int gm) {
    constexpr int KT = KTOT / 32;            // 24 (GEMM1) / 96 (GEMM2), both even
    constexpr int NBN = NTOT / 128;
    __shared__ __align__(1024) ushort As0[128 * 32];   // 8 KB each
    __shared__ __align__(1024) ushort As1[128 * 32];
    __shared__ __align__(1024) ushort Bs0[128 * 32];
    __shared__ __align__(1024) ushort Bs1[128 * 32];

    // bijective XCD-chunked swizzle (gridDim.x % 8 == 0)
    const int q = gridDim.x >> 3;
    const int id2 = (blockIdx.x & 7) * q + (blockIdx.x >> 3);
    int mb, nb;
    if (MFAST) {
        // grouped m-fastest: group = gm consecutive mbs; within group, mb fastest
        int bpg = gm * NBN;
        int g = id2 / bpg, r = id2 - g * bpg;
        nb = r / gm;
        mb = g * gm + (r - nb * gm);
    } else {
        mb = id2 / NBN;
        nb = id2 - mb * NBN;
    }
    const int e = eBase + mb / (ROWS_PER_E / 128);
    const int m0 = mb * 128;                     // chunk-local row base
    const int rbase = eBase * ROWS_PER_E + m0;   // global expert-row base
    const int n0 = nb * 128;
    const ushort* Bt = wtBase + (size_t)e * KTOT * NTOT;
    const float* bias = biasBase + (size_t)e * NTOT;

    const int t = threadIdx.x, lane = t & 63, wave = t >> 6;
    const int g16 = lane >> 2;         // row within 16-row gload slab
    const int p4 = lane & 3;           // physical 16B chunk this lane fills
    const int swz = ((p4 ^ ((g16 >> 1) & 3)) << 4);   // parity-safe XOR key

    // staging: wave w covers A rows [w*32,w*32+32) and B rows [w*32,w*32+32),
    // 16 rows per gload -> 2 A-gloads + 2 B-gloads per wave per K-tile
    const char* aS[2];
    const char* bS[2];
    #pragma unroll
    for (int j = 0; j < 2; j++) {
        int r = wave * 32 + j * 16 + g16;
        size_t arow;
        if (MODE == 0) { int tk = slot_map[rbase + r]; arow = (size_t)(tk < 0 ? 0 : tk); }
        else           { arow = (size_t)(m0 + r); }
        aS[j] = (const char*)(Asrc + arow * KTOT) + swz;
        bS[j] = (const char*)(Bt + (size_t)(n0 + r) * KTOT) + swz;
    }

    auto STAGE = [&](int kt, ushort* WA, ushort* WB) {
        size_t o = (size_t)kt * 64;    // 32 bf16 = 64 B per row per K-tile
        #pragma unroll
        for (int j = 0; j < 2; j++) {
            gload16(aS[j] + o, WA + (wave * 32 + j * 16) * 32);
            gload16(bS[j] + o, WB + (wave * 32 + j * 16) * 32);
        }
    };

    const int wr = wave >> 1, wc = wave & 1;   // wave grid 2(m) x 2(n), out 64x64
    const int l15 = lane & 15, kq = lane >> 4;
    const int ch = (kq ^ ((l15 >> 1) & 3)) << 3;   // parity-safe read swizzle

    f32x4 acc[4][4] = {};

    // body for K-tile kt: stage kt+1 into W first, compute from R, one sync point
    auto BODY = [&](int kt, const ushort* RA, const ushort* RB, ushort* WA, ushort* WB) {
        const bool last = (kt + 1 >= KT);
        if (!last) STAGE(kt + 1, WA, WB);      // issue first: full-tile flight
        bf16x8 af[4], bfr[4];
        #pragma unroll
        for (int mi = 0; mi < 4; mi++)
            af[mi] = *(const bf16x8*)(&RA[(wr * 64 + mi * 16 + l15) * 32 + ch]);
        #pragma unroll
        for (int nf = 0; nf < 4; nf++)
            bfr[nf] = *(const bf16x8*)(&RB[(wc * 64 + nf * 16 + l15) * 32 + ch]);
        __builtin_amdgcn_s_setprio(1);
        #pragma unroll
        for (int mi = 0; mi < 4; mi++) {
            #pragma unroll
            for (int nf = 0; nf < 4; nf++)
                acc[mi][nf] = __builtin_amdgcn_mfma_f32_16x16x32_bf16(
                    af[mi], bfr[nf], acc[mi][nf], 0, 0, 0);
        }
        __builtin_amdgcn_s_setprio(0);
        if (!last) {
            asm volatile("s_waitcnt vmcnt(0)" ::: "memory");   // kt+1's 4 gloads landed
            __builtin_amdgcn_s_barrier();                      // all waves ready; reads done
        }
    };

    // prologue: stage tile 0, drain, rendezvous
    STAGE(0, As0, Bs0);
    asm volatile("s_waitcnt vmcnt(0)" ::: "memory");
    __builtin_amdgcn_s_barrier();

    for (int kt = 0; kt < KT; kt += 2) {
        BODY(kt,     As0, Bs0, As1, Bs1);
        BODY(kt + 1, As1, Bs1, As0, Bs0);
    }

    // epilogue: C/D layout col=lane&15, row=(lane>>4)*4+j  (verified)
    const int ccolb = n0 + wc * 64 + l15;
    float bv[4];
    #pragma unroll
    for (int nf = 0; nf < 4; nf++) bv[nf] = bias[ccolb + nf * 16];

    const int rowb = (MODE == 0 ? m0 : rbase) + wr * 64 + (lane >> 4) * 4;
    #pragma unroll
    for (int mi = 0; mi < 4; mi++) {
        #pragma unroll
        for (int j = 0; j < 4; j++) {
            size_t roff = (size_t)(rowb + mi * 16 + j) * NTOT;
            #pragma unroll
            for (int nf = 0; nf < 4; nf++) {
                float v = acc[mi][nf][j] + bv[nf];
                if (MODE == 0) v = gelu_f(v);
                Cdst[roff + ccolb + nf * 16] = f2bf(v);
            }
        }
    }
}

// ---------------- combine: out[token] = g1*y[r1] + g2*y[r2] ----------------
__global__ void k_combine(const ushort* __restrict__ y,
                          const int* __restrict__ r1, const int* __restrict__ r2,
                          const float* __restrict__ g1, const float* __restrict__ g2,
                          float* __restrict__ out) {
    int t = blockIdx.x;
    int d = threadIdx.x;          // 192 threads, 4 floats each
    int a = r1[t], b = r2[t];
    float wa = g1[t], wb = g2[t];
    size_t opos;
    if (t < NDET) { int bb = t >> 10, s = t & 1023; opos = ((size_t)bb * 1280 + s) * 768; }
    else { int tt = t - NDET; int bb = tt >> 8, s = tt & 255; opos = ((size_t)bb * 1280 + 1024 + s) * 768; }
    int di = d * 4;
    float4 o = make_float4(0.f, 0.f, 0.f, 0.f);
    if (a >= 0) {
        uint2 v = *(const uint2*)(y + (size_t)a * 768 + di);
        o.x += wa * bf2f(v.x & 0xffffu); o.y += wa * bf2f(v.x >> 16);
        o.z += wa * bf2f(v.y & 0xffffu); o.w += wa * bf2f(v.y >> 16);
    }
    if (b >= 0) {
        uint2 v = *(const uint2*)(y + (size_t)b * 768 + di);
        o.x += wb * bf2f(v.x & 0xffffu); o.y += wb * bf2f(v.x >> 16);
        o.z += wb * bf2f(v.y & 0xffffu); o.w += wb * bf2f(v.y >> 16);
    }
    *(float4*)(out + opos + di) = o;
}

extern "C" void kernel_launch(void* const* d_in, const int* in_sizes, int n_in,
                              void* d_out, int out_size, void* d_ws, size_t ws_size,
                              hipStream_t stream) {
    const float* xd  = (const float*)d_in[0];
    const float* xc  = (const float*)d_in[1];
    const float* wrd = (const float*)d_in[2];
    const float* wrc = (const float*)d_in[3];
    const float* w1  = (const float*)d_in[4];
    const float* b1  = (const float*)d_in[5];
    const float* w2  = (const float*)d_in[6];
    const float* b2  = (const float*)d_in[7];
    float* out = (float*)d_out;

    size_t off = 0;
    char* base = (char*)d_ws;
    auto alloc = [&](size_t bytes) -> char* {
        char* r = base + off;
        off += (bytes + 255) & ~(size_t)255;
        return r;
    };
    ushort* xbf = (ushort*)alloc((size_t)NTOK * DMODEL * 2);
    ushort* w1t = (ushort*)alloc((size_t)NE * MLPDIM * DMODEL * 2);
    ushort* w2t = (ushort*)alloc((size_t)NE * DMODEL * MLPDIM * 2);
    ushort* y   = (ushort*)alloc((size_t)TOT_ROWS * DMODEL * 2);
    int*   slot_map = (int*)alloc((size_t)TOT_ROWS * 4);
    int*   e1 = (int*)alloc((size_t)NTOK * 4);
    int*   e2 = (int*)alloc((size_t)NTOK * 4);
    float* g1 = (float*)alloc((size_t)NTOK * 4);
    float* g2 = (float*)alloc((size_t)NTOK * 4);
    int*   r1 = (int*)alloc((size_t)NTOK * 4);
    int*   r2 = (int*)alloc((size_t)NTOK * 4);

    // pick the largest expert-chunk whose h buffer fits the workspace
    const size_t h_per_e = (size_t)ROWS_PER_E * MLPDIM * 2;   // 31.5 MB
    int chunkE = 0;
    for (int c = NE; c >= 2; c >>= 1)
        if (off + c * h_per_e <= ws_size) { chunkE = c; break; }
    if (!chunkE) return;
    ushort* h = (ushort*)alloc((size_t)chunkE * h_per_e);

    hipMemsetAsync(slot_map, 0xFF, (size_t)TOT_ROWS * 4, stream);   // -1 = empty

    k_router<<<NTOK / 4, 256, 0, stream>>>(xd, xc, wrd, wrc, xbf, e1, e2, g1, g2);
    k_transpose_bf<<<dim3(MLPDIM / 32, DMODEL / 32, NE), dim3(8, 32), 0, stream>>>(w1, w1t, DMODEL, MLPDIM);
    k_transpose_bf<<<dim3(DMODEL / 32, MLPDIM / 32, NE), dim3(8, 32), 0, stream>>>(w2, w2t, MLPDIM, DMODEL);
    k_scan<<<24, 64, 0, stream>>>(e1, e2, slot_map, r1, r2);

    for (int e0 = 0; e0 < NE; e0 += chunkE) {
        int nmb = chunkE * (ROWS_PER_E / 128);               // 128-row m-blocks in chunk
        int gm = (nmb % 20 == 0) ? 20 : 10;                  // A-group: gm*192KB <= 4MB L2
        k_gemm<DMODEL, MLPDIM, 0, true><<<nmb * (MLPDIM / 128), 256, 0, stream>>>(
            xbf, slot_map, w1t, b1, h, e0, gm);
        k_gemm<MLPDIM, DMODEL, 1, false><<<nmb * (DMODEL / 128), 256, 0, stream>>>(
            h, slot_map, w2t, b2, y, e0, 0);
    }

    k_combine<<<NTOK, 192, 0, stream>>>(y, r1, r2, g1, g2, out);
}

// Round 16
// 567.267 us; speedup vs baseline: 1.1278x; 1.1206x over previous
//
#include <hip/hip_runtime.h>
#include <cstdint>
#include <cstddef>

#define NE 8
#define DMODEL 768
#define MLPDIM 3072
#define NDET 16384
#define NCLS 4096
#define NTOK 20480
#define ROWS_PER_E 5120   /* 16*256 (det) + 8*128 (cls) */
#define TOT_ROWS 40960

typedef float f32x4 __attribute__((ext_vector_type(4)));
typedef __bf16 bf16x8 __attribute__((ext_vector_type(8)));

__device__ __forceinline__ unsigned short f2bf(float f) {
    unsigned u = __float_as_uint(f);
    u += 0x7FFFu + ((u >> 16) & 1u);   // RNE
    return (unsigned short)(u >> 16);
}
__device__ __forceinline__ float bf2f(unsigned v) {
    return __uint_as_float(v << 16);
}
__device__ __forceinline__ float gelu_f(float x) {
    // jax.nn.gelu approximate=True. Exact identity: 0.5*(1+tanh(u)) == sigmoid(2u)
    // => gelu = x / (1 + exp(-2u)), u = 0.79788456*(x + 0.044715 x^3).
    float u = x * (0.7978845608028654f + 0.0356774081099f * x * x);
    return x * __frcp_rn(1.0f + __expf(-2.0f * u));
}

// async global->LDS, 16B per lane; dst is wave-uniform base, HW adds lane*16
__device__ __forceinline__ void gload16(const void* g, void* l) {
    __builtin_amdgcn_global_load_lds(
        (const __attribute__((address_space(1))) unsigned int*)g,
        (__attribute__((address_space(3))) unsigned int*)l, 16, 0, 0);
}

// ---------------- router (fp32) + x->bf16 conversion fused ----------------
__global__ void k_router(const float* __restrict__ xd, const float* __restrict__ xc,
                         const float* __restrict__ wrd, const float* __restrict__ wrc,
                         ushort* __restrict__ xbf,
                         int* __restrict__ e1, int* __restrict__ e2,
                         float* __restrict__ g1, float* __restrict__ g2) {
    int wave = threadIdx.x >> 6, lane = threadIdx.x & 63;
    int t = blockIdx.x * 4 + wave;
    if (t >= NTOK) return;
    const float* xrow;
    const float* w;
    if (t < NDET) { xrow = xd + (size_t)t * DMODEL; w = wrd; }
    else          { xrow = xc + (size_t)(t - NDET) * DMODEL; w = wrc; }
    ushort* xbrow = xbf + (size_t)t * DMODEL;
    float acc[8];
    #pragma unroll
    for (int e = 0; e < 8; e++) acc[e] = 0.0f;
    #pragma unroll
    for (int kk = 0; kk < DMODEL / 64; kk++) {
        int k = kk * 64 + lane;
        float xv = xrow[k];
        xbrow[k] = f2bf(xv);              // fused bf16 conversion
        const float* wr = w + k * 8;
        #pragma unroll
        for (int e = 0; e < 8; e++) acc[e] += xv * wr[e];
    }
    #pragma unroll
    for (int e = 0; e < 8; e++) {
        #pragma unroll
        for (int off = 32; off > 0; off >>= 1) acc[e] += __shfl_xor(acc[e], off);
    }
    // top-2 with lower-index tie-break (lax.top_k)
    int i1 = 0; float v1 = acc[0];
    #pragma unroll
    for (int e = 1; e < 8; e++) if (acc[e] > v1) { v1 = acc[e]; i1 = e; }
    int i2 = -1; float v2 = -1e30f;
    #pragma unroll
    for (int e = 0; e < 8; e++) if (e != i1 && acc[e] > v2) { v2 = acc[e]; i2 = e; }
    float Z = 0.0f;
    #pragma unroll
    for (int e = 0; e < 8; e++) Z += __expf(acc[e] - v1);
    if (lane == 0) {
        e1[t] = i1; e2[t] = i2;
        g1[t] = 1.0f / Z;
        g2[t] = __expf(v2 - v1) / Z;
    }
}

// ---------------- w [E][K][N] fp32 -> [E][N][K] bf16 (float4 loads) ----------------
__global__ void k_transpose_bf(const float* __restrict__ in, ushort* __restrict__ out,
                               int K, int N) {
    __shared__ float tile[32][33];
    int e = blockIdx.z;
    const float* A = in + (size_t)e * K * N;
    ushort* B = out + (size_t)e * N * K;
    int n0 = blockIdx.x * 32, k0 = blockIdx.y * 32;
    int tx = threadIdx.x, ty = threadIdx.y;   // (8,32)
    float4 v = *(const float4*)(A + (size_t)(k0 + ty) * N + n0 + tx * 4);
    tile[ty][tx * 4 + 0] = v.x; tile[ty][tx * 4 + 1] = v.y;
    tile[ty][tx * 4 + 2] = v.z; tile[ty][tx * 4 + 3] = v.w;
    __syncthreads();
    ushort4 o;
    o.x = f2bf(tile[tx * 4 + 0][ty]);
    o.y = f2bf(tile[tx * 4 + 1][ty]);
    o.z = f2bf(tile[tx * 4 + 2][ty]);
    o.w = f2bf(tile[tx * 4 + 3][ty]);
    *(ushort4*)(B + (size_t)(n0 + ty) * K + k0 + tx * 4) = o;
}

// ---------------- capacity scan: one wave per group, k-major order ----------------
__global__ void k_scan(const int* __restrict__ e1, const int* __restrict__ e2,
                       int* __restrict__ slot_map, int* __restrict__ r1, int* __restrict__ r2) {
    int g = blockIdx.x;          // 0..15 det, 16..23 cls
    int lane = threadIdx.x;      // 64 threads
    int S, C, base;
    if (g < 16) { S = 1024; C = 256; base = g * 1024; }
    else        { S = 512;  C = 128; base = NDET + (g - 16) * 512; }
    int cnt[8];
    #pragma unroll
    for (int e = 0; e < 8; e++) cnt[e] = 0;
    unsigned long long lower = (lane == 0) ? 0ULL : ((~0ULL) >> (64 - lane));
    int nch = (2 * S) >> 6;
    for (int ch = 0; ch < nch; ch++) {
        int n = ch * 64 + lane;
        int k = (n >= S) ? 1 : 0;
        int s = n - k * S;
        int tok = base + s;
        int e = k ? e2[tok] : e1[tok];
        int pos = 0;
        #pragma unroll
        for (int ee = 0; ee < 8; ee++) {
            unsigned long long m = __ballot(e == ee);
            if (e == ee) pos = cnt[ee] + __popcll(m & lower);
            cnt[ee] += __popcll(m);
        }
        int r = -1;
        if (pos < C) {
            int local = (g < 16) ? (g * 256 + pos) : (4096 + (g - 16) * 128 + pos);
            r = e * ROWS_PER_E + local;
            slot_map[r] = tok;
        }
        if (k == 0) r1[tok] = r; else r2[tok] = r;
    }
}

// ---------------- GEMM: 128x128 tile, BK=64, 4 waves, per-wave 64x64 ----------------
// R13 chassis (best measured: 569us total, 126us/dispatch, MfmaUtil 33.7%, 0
// conflicts) + MFAST now on BOTH GEMMs:
//  GEMM1 gm=20 (20 A-panels x 192KB = 3.84MB <= 4MB L2) [R13-verified: FETCH
//  195->144MB], GEMM2 gm=5 (5 h-panels x 768KB = 3.84MB) — same permutation,
//  keeps A-group L2-resident so each B-panel is fetched ~once per group
//  (n-fastest swept 6 w2t panels = 4.6MB > 4MB every mb).
// Loop: bar(drain); read kc0; MFMA kc0; read kc1; bar; ISSUE(ks+1); MFMA kc1.
// XOR-8 swizzle (0-conflict, measured r3-r13). Epilogue layout verified r1.
// MODE 0: A = xbf gathered via slot_map -> h=gelu(A@B+b) (chunk-local rows)
// MODE 1: A = h (chunk-local) -> y[global row] = A@B+b
template<int KTOT, int NTOT, int MODE, bool MFAST>
__global__ __launch_bounds__(256, 4) void k_gemm(
    const ushort* __restrict__ Asrc, const int* __restrict__ slot_map,
    const ushort* __restrict__ wtBase, const float* __restrict__ biasBase,
    ushort* __restrict__ Cdst, int eBase, int gm) {
    constexpr int KT = KTOT / 64;            // 12 (GEMM1) / 48 (GEMM2)
    constexpr int NBN = NTOT / 128;
    __shared__ __align__(1024) ushort As[128 * 64];   // 16 KB
    __shared__ __align__(1024) ushort Bs[128 * 64];   // 16 KB

    // bijective XCD-chunked swizzle (gridDim.x % 8 == 0)
    const int q = gridDim.x >> 3;
    const int id2 = (blockIdx.x & 7) * q + (blockIdx.x >> 3);
    int mb, nb;
    if (MFAST) {
        // grouped m-fastest: group = gm consecutive mbs; within group, mb fastest
        int bpg = gm * NBN;
        int g = id2 / bpg, r = id2 - g * bpg;
        nb = r / gm;
        mb = g * gm + (r - nb * gm);
    } else {
        mb = id2 / NBN;
        nb = id2 - mb * NBN;
    }
    const int e = eBase + mb / (ROWS_PER_E / 128);
    const int m0 = mb * 128;                     // chunk-local row base
    const int rbase = eBase * ROWS_PER_E + m0;   // global expert-row base
    const int n0 = nb * 128;
    const ushort* Bt = wtBase + (size_t)e * KTOT * NTOT;
    const float* bias = biasBase + (size_t)e * NTOT;

    const int t = threadIdx.x, lane = t & 63, wave = t >> 6;
    const int g8 = lane >> 3;          // row within 8-row staging group
    const int p8 = lane & 7;           // physical 16B chunk this lane fills
    const int swz = ((p8 ^ g8) << 4);  // byte offset of LOGICAL chunk to fetch

    // staging: wave w covers A rows [w*32,w*32+32) and B rows [w*32,w*32+32),
    // 8 rows per gload -> 4 A-gloads + 4 B-gloads per wave per K-tile
    const char* aS[4];
    const char* bS[4];
    #pragma unroll
    for (int j = 0; j < 4; j++) {
        int r = wave * 32 + j * 8 + g8;
        size_t arow;
        if (MODE == 0) { int tk = slot_map[rbase + r]; arow = (size_t)(tk < 0 ? 0 : tk); }
        else           { arow = (size_t)(m0 + r); }
        aS[j] = (const char*)(Asrc + arow * KTOT) + swz;
        bS[j] = (const char*)(Bt + (size_t)(n0 + r) * KTOT) + swz;
    }

    auto ISSUE = [&](int kt) {
        size_t o = (size_t)kt * 128;   // 64 bf16 = 128 B per row per K-tile
        #pragma unroll
        for (int j = 0; j < 4; j++) {
            gload16(aS[j] + o, As + (wave * 32 + j * 8) * 64);
            gload16(bS[j] + o, Bs + (wave * 32 + j * 8) * 64);
        }
    };

    const int wr = wave >> 1, wc = wave & 1;   // wave grid 2(m) x 2(n), out 64x64
    const int l15 = lane & 15, kq = lane >> 4, l7 = lane & 7;
    const int ch[2] = { ((kq) ^ l7) << 3, ((4 + kq) ^ l7) << 3 };  // swizzled k-chunks

    f32x4 acc[4][4] = {};

    ISSUE(0);
    for (int ks = 0; ks < KT; ks++) {
        __syncthreads();               // drains vmcnt: tile ks visible in LDS
        // ---- kc = 0 ----
        bf16x8 af0[4], bf0[4];
        #pragma unroll
        for (int mi = 0; mi < 4; mi++)
            af0[mi] = *(const bf16x8*)(&As[(wr * 64 + mi * 16 + l15) * 64 + ch[0]]);
        #pragma unroll
        for (int nf = 0; nf < 4; nf++)
            bf0[nf] = *(const bf16x8*)(&Bs[(wc * 64 + nf * 16 + l15) * 64 + ch[0]]);
        __builtin_amdgcn_s_setprio(1);
        #pragma unroll
        for (int mi = 0; mi < 4; mi++) {
            #pragma unroll
            for (int nf = 0; nf < 4; nf++)
                acc[mi][nf] = __builtin_amdgcn_mfma_f32_16x16x32_bf16(
                    af0[mi], bf0[nf], acc[mi][nf], 0, 0, 0);
        }
        __builtin_amdgcn_s_setprio(0);
        // ---- kc = 1 ----
        bf16x8 af1[4], bf1[4];
        #pragma unroll
        for (int mi = 0; mi < 4; mi++)
            af1[mi] = *(const bf16x8*)(&As[(wr * 64 + mi * 16 + l15) * 64 + ch[1]]);
        #pragma unroll
        for (int nf = 0; nf < 4; nf++)
            bf1[nf] = *(const bf16x8*)(&Bs[(wc * 64 + nf * 16 + l15) * 64 + ch[1]]);
        __syncthreads();               // all waves done reading LDS tile ks
        if (ks + 1 < KT) ISSUE(ks + 1);   // loads fly under kc1 MFMA + other blocks
        __builtin_amdgcn_s_setprio(1);
        #pragma unroll
        for (int mi = 0; mi < 4; mi++) {
            #pragma unroll
            for (int nf = 0; nf < 4; nf++)
                acc[mi][nf] = __builtin_amdgcn_mfma_f32_16x16x32_bf16(
                    af1[mi], bf1[nf], acc[mi][nf], 0, 0, 0);
        }
        __builtin_amdgcn_s_setprio(0);
    }

    // epilogue: C/D layout col=lane&15, row=(lane>>4)*4+j  (verified)
    const int ccolb = n0 + wc * 64 + l15;
    float bv[4];
    #pragma unroll
    for (int nf = 0; nf < 4; nf++) bv[nf] = bias[ccolb + nf * 16];

    const int rowb = (MODE == 0 ? m0 : rbase) + wr * 64 + (lane >> 4) * 4;
    #pragma unroll
    for (int mi = 0; mi < 4; mi++) {
        #pragma unroll
        for (int j = 0; j < 4; j++) {
            size_t roff = (size_t)(rowb + mi * 16 + j) * NTOT;
            #pragma unroll
            for (int nf = 0; nf < 4; nf++) {
                float v = acc[mi][nf][j] + bv[nf];
                if (MODE == 0) v = gelu_f(v);
                Cdst[roff + ccolb + nf * 16] = f2bf(v);
            }
        }
    }
}

// ---------------- combine: out[token] = g1*y[r1] + g2*y[r2] ----------------
__global__ void k_combine(const ushort* __restrict__ y,
                          const int* __restrict__ r1, const int* __restrict__ r2,
                          const float* __restrict__ g1, const float* __restrict__ g2,
                          float* __restrict__ out) {
    int t = blockIdx.x;
    int d = threadIdx.x;          // 192 threads, 4 floats each
    int a = r1[t], b = r2[t];
    float wa = g1[t], wb = g2[t];
    size_t opos;
    if (t < NDET) { int bb = t >> 10, s = t & 1023; opos = ((size_t)bb * 1280 + s) * 768; }
    else { int tt = t - NDET; int bb = tt >> 8, s = tt & 255; opos = ((size_t)bb * 1280 + 1024 + s) * 768; }
    int di = d * 4;
    float4 o = make_float4(0.f, 0.f, 0.f, 0.f);
    if (a >= 0) {
        uint2 v = *(const uint2*)(y + (size_t)a * 768 + di);
        o.x += wa * bf2f(v.x & 0xffffu); o.y += wa * bf2f(v.x >> 16);
        o.z += wa * bf2f(v.y & 0xffffu); o.w += wa * bf2f(v.y >> 16);
    }
    if (b >= 0) {
        uint2 v = *(const uint2*)(y + (size_t)b * 768 + di);
        o.x += wb * bf2f(v.x & 0xffffu); o.y += wb * bf2f(v.x >> 16);
        o.z += wb * bf2f(v.y & 0xffffu); o.w += wb * bf2f(v.y >> 16);
    }
    *(float4*)(out + opos + di) = o;
}

extern "C" void kernel_launch(void* const* d_in, const int* in_sizes, int n_in,
                              void* d_out, int out_size, void* d_ws, size_t ws_size,
                              hipStream_t stream) {
    const float* xd  = (const float*)d_in[0];
    const float* xc  = (const float*)d_in[1];
    const float* wrd = (const float*)d_in[2];
    const float* wrc = (const float*)d_in[3];
    const float* w1  = (const float*)d_in[4];
    const float* b1  = (const float*)d_in[5];
    const float* w2  = (const float*)d_in[6];
    const float* b2  = (const float*)d_in[7];
    float* out = (float*)d_out;

    size_t off = 0;
    char* base = (char*)d_ws;
    auto alloc = [&](size_t bytes) -> char* {
        char* r = base + off;
        off += (bytes + 255) & ~(size_t)255;
        return r;
    };
    ushort* xbf = (ushort*)alloc((size_t)NTOK * DMODEL * 2);
    ushort* w1t = (ushort*)alloc((size_t)NE * MLPDIM * DMODEL * 2);
    ushort* w2t = (ushort*)alloc((size_t)NE * DMODEL * MLPDIM * 2);
    ushort* y   = (ushort*)alloc((size_t)TOT_ROWS * DMODEL * 2);
    int*   slot_map = (int*)alloc((size_t)TOT_ROWS * 4);
    int*   e1 = (int*)alloc((size_t)NTOK * 4);
    int*   e2 = (int*)alloc((size_t)NTOK * 4);
    float* g1 = (float*)alloc((size_t)NTOK * 4);
    float* g2 = (float*)alloc((size_t)NTOK * 4);
    int*   r1 = (int*)alloc((size_t)NTOK * 4);
    int*   r2 = (int*)alloc((size_t)NTOK * 4);

    // pick the largest expert-chunk whose h buffer fits the workspace
    const size_t h_per_e = (size_t)ROWS_PER_E * MLPDIM * 2;   // 31.5 MB
    int chunkE = 0;
    for (int c = NE; c >= 2; c >>= 1)
        if (off + c * h_per_e <= ws_size) { chunkE = c; break; }
    if (!chunkE) return;
    ushort* h = (ushort*)alloc((size_t)chunkE * h_per_e);

    hipMemsetAsync(slot_map, 0xFF, (size_t)TOT_ROWS * 4, stream);   // -1 = empty

    k_router<<<NTOK / 4, 256, 0, stream>>>(xd, xc, wrd, wrc, xbf, e1, e2, g1, g2);
    k_transpose_bf<<<dim3(MLPDIM / 32, DMODEL / 32, NE), dim3(8, 32), 0, stream>>>(w1, w1t, DMODEL, MLPDIM);
    k_transpose_bf<<<dim3(DMODEL / 32, MLPDIM / 32, NE), dim3(8, 32), 0, stream>>>(w2, w2t, MLPDIM, DMODEL);
    k_scan<<<24, 64, 0, stream>>>(e1, e2, slot_map, r1, r2);

    for (int e0 = 0; e0 < NE; e0 += chunkE) {
        int nmb = chunkE * (ROWS_PER_E / 128);               // 128-row m-blocks in chunk
        int gm1 = (nmb % 20 == 0) ? 20 : 10;                 // GEMM1 A-group: 20*192KB <= 4MB
        k_gemm<DMODEL, MLPDIM, 0, true><<<nmb * (MLPDIM / 128), 256, 0, stream>>>(
            xbf, slot_map, w1t, b1, h, e0, gm1);
        k_gemm<MLPDIM, DMODEL, 1, true><<<nmb * (DMODEL / 128), 256, 0, stream>>>(
            h, slot_map, w2t, b2, y, e0, 5);                 // GEMM2 A-group: 5*768KB <= 4MB
    }

    k_combine<<<NTOK, 192, 0, stream>>>(y, r1, r2, g1, g2, out);
}